// Round 10
// baseline (496.254 us; speedup 1.0000x reference)
//
#include <hip/hip_runtime.h>

#define HH 50
#define NB 8            // batch elements per block
#define TT 512
#define NTH 256         // 4 waves, one per SIMD; tiles {4,3,3,3}
#define NT 13           // tiles of 4 units (52 >= 50)
#define AS 136          // shorts per activation row: 128 k-slots + 8 pad (272B; odd 16B-groups)
#define XS (TT * 3 + 4) // x-stash row stride (fp16 elements)
#define NFRAG (NT * 12)

typedef __attribute__((ext_vector_type(8))) _Float16 half8;
typedef __attribute__((ext_vector_type(4))) float f32x4;

#define MFMA16(a, b, c) __builtin_amdgcn_mfma_f32_16x16x32_f16((a), (b), (c), 0, 0, 0)

#define WLO_SCALE 2048.0f   // lo slots still written by prep (layout kept); unused by main

__device__ __forceinline__ unsigned short f2h(float f) {
    const _Float16 h = (_Float16)f;               // v_cvt_f16_f32, RTNE
    return __builtin_bit_cast(unsigned short, h);
}
// clamp-free: saturates correctly through inf (rcp(inf)=0), no NaN for finite v
__device__ __forceinline__ float fsig(float v) {
    return __builtin_amdgcn_rcpf(1.f + __builtin_amdgcn_exp2f(v * -1.442695041f));
}
__device__ __forceinline__ float ftanh(float v) {
    return fmaf(-2.f, __builtin_amdgcn_rcpf(1.f + __builtin_amdgcn_exp2f(v * 2.885390082f)), 1.f);
}

// ---------------- prep kernel: gate-interleaved fp16 A-operand weight fragments ----------------
// (unchanged; lo slots written but unused)
__global__ void prep_frags(
    const float* __restrict__ W_ih0, const float* __restrict__ W_hh0,
    const float* __restrict__ b_ih0, const float* __restrict__ b_hh0,
    const float* __restrict__ W_ih1, const float* __restrict__ W_hh1,
    const float* __restrict__ b_ih1, const float* __restrict__ b_hh1,
    unsigned short* __restrict__ ws)
{
    const int idx = blockIdx.x * blockDim.x + threadIdx.x;
    if (idx >= NFRAG * 64) return;
    const int lane = idx & 63;
    const int fid  = idx >> 6;
    const int nt   = fid / 12;
    const int slot = fid - nt * 12;
    const int r    = lane & 15;
    const int q    = lane >> 4;
    const int u    = nt * 4 + (r >> 2);
    const int gi   = r & 3;
    const int n    = gi * HH + u;          // original weight row
    const int layer = (slot < 4) ? 0 : 1;
    const int s     = (slot < 4) ? slot : (slot - 4);
    const int kt    = s >> 1;
    const int ishi  = !(s & 1);

    unsigned short v[8];
    #pragma unroll
    for (int jj = 0; jj < 8; ++jj) {
        const int k = kt * 32 + q * 8 + jj;
        float w = 0.f;
        if (u < HH) {
            if (layer == 0) {
                if (k < 50)       w = W_hh0[n * 50 + k];
                else if (k < 53)  w = W_ih0[n * 3 + (k - 50)];
                else if (k == 53) w = b_ih0[n] + b_hh0[n];
            } else {
                if (k < 50)        w = W_ih1[n * 50 + k];
                else if (k < 100)  w = W_hh1[n * 50 + (k - 50)];
                else if (k == 100) w = b_ih1[n] + b_hh1[n];
            }
        }
        if (ishi) {
            v[jj] = f2h(w);
        } else {
            const float hi = (float)(_Float16)w;
            v[jj] = f2h((w - hi) * WLO_SCALE);
        }
    }
    #pragma unroll
    for (int jj = 0; jj < 8; ++jj)
        ws[((size_t)fid * 64 + lane) * 8 + jj] = v[jj];
}

// ---------------- fused tile step: 6 fp16 MFMA -> cell -> fp16 writeback (verbatim v16) ----------------
__device__ __forceinline__ void tile_step(
    const int nt, const int t,
    const half8 ah[4],
    const half8 w0h[2], const half8 w1h[4],
    float& cst, const int col, const int q4,
    unsigned short* dA, float* hBf)
{
    f32x4 a0 = {0.f,0.f,0.f,0.f};
    f32x4 a1 = {0.f,0.f,0.f,0.f};
    #pragma unroll
    for (int kt = 0; kt < 2; ++kt)                   // layer0 gates (K = 64)
        a0 = MFMA16(w0h[kt], ah[kt], a0);
    #pragma unroll
    for (int kt = 0; kt < 4; ++kt)                   // layer1 gates (K = 128)
        a1 = MFMA16(w1h[kt], ah[kt], a1);

    const bool isL0 = (col < 8);
    const bool run = isL0 ? (t < TT) : (t > 0);      // uniform true for 0<t<TT
    if (run) {
        const float g0 = isL0 ? a0[0] : a1[0];
        const float g1 = isL0 ? a0[1] : a1[1];
        const float g2 = isL0 ? a0[2] : a1[2];
        const float g3 = isL0 ? a0[3] : a1[3];
        const float ii = fsig(g0), ff = fsig(g1);
        const float gg = ftanh(g2), oo = fsig(g3);
        const float c = ff * cst + ii * gg;
        cst = c;
        const float h = oo * ftanh(c);
        const int u = nt * 4 + q4;
        if (u < HH) {
            const unsigned short hs = f2h(h);
            if (isL0) {
                dA[col * AS + u] = hs;               // L0 recurrent
                dA[(col + 8) * AS + u] = hs;         // L1 input
            } else {
                dA[col * AS + 50 + u] = hs;          // L1 recurrent
                if (t == TT) hBf[(col - 8) * 52 + u] = h;
            }
        }
    }
}

// ---------------- main kernel: v16 numerics/layout, 4 waves x {4,3,3,3} tiles ----------------
// Per-SIMD compute is unchanged (it was already {4,3,3,3.x} tile-sets via wave pairing);
// what changes: DS reads halve (4 reads/wave amortize over 3.25 tiles vs 1.6), wave
// imbalance drops 2:1 -> 4:3, barrier skew shrinks. 1 wave/SIMD exposes ds_read latency,
// mitigated by 3-4 independent tiles of in-wave ILP.
__global__ __launch_bounds__(NTH, 1) void lstm_mfma_v17(
    const float* __restrict__ x,
    const unsigned short* __restrict__ ws,
    const float* __restrict__ fc_w, const float* __restrict__ fc_b,
    float* __restrict__ out)
{
    __shared__ __align__(16) unsigned short Ah[2][16 * AS];
    __shared__ float hBf[NB * 52];
    __shared__ unsigned short xstash[NB * XS];        // 8 x 1540 fp16 = 24.6 KB

    const int tid  = threadIdx.x;
    const int lane = tid & 63;
    const int wid  = tid >> 6;                        // 0..3
    const int col  = lane & 15;
    const int q4   = lane >> 4;
    const int b0   = blockIdx.x * NB;

    for (int i = tid; i < 16 * AS; i += NTH) {
        Ah[0][i] = 0; Ah[1][i] = 0;
    }

    // ---- preload + fp16-convert the block's x slab (contiguous 48 KB) ----
    {
        const float* xg = x + (size_t)b0 * (TT * 3);
        for (int i = tid; i < (NB * TT * 3) / 4; i += NTH) {   // 3072 float4s, 12 iters
            const float4 v4 = ((const float4*)xg)[i];
            const int e = i * 4;
            #pragma unroll
            for (int j = 0; j < 4; ++j) {
                const int b = (e + j) / (TT * 3);
                const int r = (e + j) - b * (TT * 3);
                xstash[b * XS + r] = f2h((&v4.x)[j]);
            }
        }
    }
    __syncthreads();

    if (tid < NB) {                                   // bias columns (fp16 1.0), both buffers
        Ah[0][tid * AS + 53] = 0x3C00;        Ah[1][tid * AS + 53] = 0x3C00;
        Ah[0][(tid + 8) * AS + 100] = 0x3C00; Ah[1][(tid + 8) * AS + 100] = 0x3C00;
    }

    // ---- weight fragments (hi only): wave 0 -> tiles 0-3; wave w>0 -> tiles 4+3(w-1)..+2 ----
    const int ntbase = (wid == 0) ? 0 : 4 + 3 * (wid - 1);
    const int ntcnt  = (wid == 0) ? 4 : 3;
    const half8* wsf = (const half8*)ws;
    half8 w0h[4][2], w1h[4][4];
    #pragma unroll
    for (int i = 0; i < 4; ++i) {
        if (i < ntcnt) {
            const size_t gb = (size_t)(ntbase + i) * (12 * 64) + lane;
            #pragma unroll
            for (int kt = 0; kt < 2; ++kt)
                w0h[i][kt] = wsf[gb + (size_t)(kt * 2 + 0) * 64];
            #pragma unroll
            for (int kt = 0; kt < 4; ++kt)
                w1h[i][kt] = wsf[gb + (size_t)(4 + kt * 2 + 0) * 64];
        }
    }

    // ---- x-writer role: wave 3 lanes 0..23 ----
    int xb = 0, xc = 0, xoff = 0;
    const bool isx = (tid >= 192 && tid < 192 + NB * 3);
    if (isx) {
        const int i = tid - 192;
        xb = i / 3; xc = i - xb * 3;
        xoff = xb * AS + 50 + xc;
        Ah[0][xoff] = xstash[xb * XS + xc];           // x(0) -> buf 0
    }
    float cs0 = 0.f, cs1 = 0.f, cs2 = 0.f, cs3 = 0.f; // c-state per owned tile slot
    __syncthreads();

    const int rbase = col * AS + q4 * 8;

    // ======== single-phase main loop: read buf p, write buf p^1, ONE barrier ========
    for (int t = 0; t <= TT; ++t) {
        const int p = t & 1;
        const unsigned short* sA = Ah[p];
        unsigned short* dA = Ah[p ^ 1];

        half8 ah[4];                                  // B-operand activation frags (4 reads/wave)
        #pragma unroll
        for (int kt = 0; kt < 4; ++kt)
            ah[kt] = *(const half8*)&sA[rbase + kt * 32];

        if (wid == 0) {
            tile_step(0, t, ah, w0h[0], w1h[0], cs0, col, q4, dA, hBf);
            tile_step(1, t, ah, w0h[1], w1h[1], cs1, col, q4, dA, hBf);
            tile_step(2, t, ah, w0h[2], w1h[2], cs2, col, q4, dA, hBf);
            tile_step(3, t, ah, w0h[3], w1h[3], cs3, col, q4, dA, hBf);
        } else {
            tile_step(ntbase + 0, t, ah, w0h[0], w1h[0], cs0, col, q4, dA, hBf);
            tile_step(ntbase + 1, t, ah, w0h[1], w1h[1], cs1, col, q4, dA, hBf);
            tile_step(ntbase + 2, t, ah, w0h[2], w1h[2], cs2, col, q4, dA, hBf);
        }

        if (isx) {                                    // stage x(t+1) from LDS stash (no vmem)
            const int tn1 = (t + 1 < TT) ? (t + 1) : (TT - 1);
            dA[xoff] = xstash[xb * XS + tn1 * 3 + xc];
        }
        __syncthreads();
    }

    // ======== final FC ========
    if (tid < NB * 3) {
        const int bb = tid / 3, o = tid - bb * 3;
        float a = fc_b[o];
        #pragma unroll
        for (int uu = 0; uu < HH; ++uu)
            a += hBf[bb * 52 + uu] * fc_w[o * HH + uu];
        out[(size_t)(b0 + bb) * 3 + o] = a;
    }
}

extern "C" void kernel_launch(void* const* d_in, const int* in_sizes, int n_in,
                              void* d_out, int out_size, void* d_ws, size_t ws_size,
                              hipStream_t stream) {
    const float* x     = (const float*)d_in[0];
    const float* W_ih0 = (const float*)d_in[1];
    const float* W_hh0 = (const float*)d_in[2];
    const float* b_ih0 = (const float*)d_in[3];
    const float* b_hh0 = (const float*)d_in[4];
    const float* W_ih1 = (const float*)d_in[5];
    const float* W_hh1 = (const float*)d_in[6];
    const float* b_ih1 = (const float*)d_in[7];
    const float* b_hh1 = (const float*)d_in[8];
    const float* fc_w  = (const float*)d_in[9];
    const float* fc_b  = (const float*)d_in[10];
    float* out = (float*)d_out;
    unsigned short* ws = (unsigned short*)d_ws;       // NFRAG*64*16 B = 156 KB

    const int prepN = NFRAG * 64;
    prep_frags<<<(prepN + 255) / 256, 256, 0, stream>>>(
        W_ih0, W_hh0, b_ih0, b_hh0, W_ih1, W_hh1, b_ih1, b_hh1, ws);

    const int B = 2048;
    dim3 grid(B / NB), block(NTH);
    lstm_mfma_v17<<<grid, block, 0, stream>>>(x, ws, fc_w, fc_b, out);
}

// Round 11
// 370.164 us; speedup vs baseline: 1.3406x; 1.3406x over previous
//
#include <hip/hip_runtime.h>

#define HH 50
#define NB 8            // batch elements per block
#define TT 512
#define NTH 512
#define NT 13           // tiles of 4 units (52 >= 50)
#define AS 136          // shorts per activation row: 128 k-slots + 8 pad (272B; odd 16B-groups)
#define XS (TT * 3 + 4) // x-stash row stride (fp16 elements)
#define NFRAG (NT * 12)

typedef __attribute__((ext_vector_type(8))) _Float16 half8;
typedef __attribute__((ext_vector_type(4))) float f32x4;

#define MFMA16(a, b, c) __builtin_amdgcn_mfma_f32_16x16x32_f16((a), (b), (c), 0, 0, 0)

__device__ __forceinline__ unsigned short f2h(float f) {
    const _Float16 h = (_Float16)f;               // v_cvt_f16_f32, RTNE
    return __builtin_bit_cast(unsigned short, h);
}
// clamp-free: saturates correctly through inf (rcp(inf)=0), no NaN for finite v
__device__ __forceinline__ float fsig(float v) {
    return __builtin_amdgcn_rcpf(1.f + __builtin_amdgcn_exp2f(v * -1.442695041f));
}
__device__ __forceinline__ float ftanh(float v) {
    return fmaf(-2.f, __builtin_amdgcn_rcpf(1.f + __builtin_amdgcn_exp2f(v * 2.885390082f)), 1.f);
}

// ---------------- prep kernel: gate-interleaved fp16 A-operand weight fragments ----------------
// hi slots only (lo slots dead since v16); lo threads exit early -> half the scattered loads.
__global__ void prep_frags(
    const float* __restrict__ W_ih0, const float* __restrict__ W_hh0,
    const float* __restrict__ b_ih0, const float* __restrict__ b_hh0,
    const float* __restrict__ W_ih1, const float* __restrict__ W_hh1,
    const float* __restrict__ b_ih1, const float* __restrict__ b_hh1,
    unsigned short* __restrict__ ws)
{
    const int idx = blockIdx.x * blockDim.x + threadIdx.x;
    if (idx >= NFRAG * 64) return;
    const int lane = idx & 63;
    const int fid  = idx >> 6;
    const int nt   = fid / 12;
    const int slot = fid - nt * 12;
    const int s    = (slot < 4) ? slot : (slot - 4);
    if (s & 1) return;                     // lo slot: dead, skip
    const int r    = lane & 15;
    const int q    = lane >> 4;
    const int u    = nt * 4 + (r >> 2);
    const int gi   = r & 3;
    const int n    = gi * HH + u;          // original weight row
    const int layer = (slot < 4) ? 0 : 1;
    const int kt    = s >> 1;

    unsigned short v[8];
    #pragma unroll
    for (int jj = 0; jj < 8; ++jj) {
        const int k = kt * 32 + q * 8 + jj;
        float w = 0.f;
        if (u < HH) {
            if (layer == 0) {
                if (k < 50)       w = W_hh0[n * 50 + k];
                else if (k < 53)  w = W_ih0[n * 3 + (k - 50)];
                else if (k == 53) w = b_ih0[n] + b_hh0[n];
            } else {
                if (k < 50)        w = W_ih1[n * 50 + k];
                else if (k < 100)  w = W_hh1[n * 50 + (k - 50)];
                else if (k == 100) w = b_ih1[n] + b_hh1[n];
            }
        }
        v[jj] = f2h(w);
    }
    #pragma unroll
    for (int jj = 0; jj < 8; ++jj)
        ws[((size_t)fid * 64 + lane) * 8 + jj] = v[jj];
}

// ---------------- fused tile step: 6 fp16 MFMA (a1 split 2+2) -> cell -> fp16 writeback ----------------
__device__ __forceinline__ void tile_step(
    const int nt, const int t,
    const half8 ah[4],
    const half8 w0h[2], const half8 w1h[4],
    float& cst, const int col, const int q4,
    unsigned short* dA, float* hBf)
{
    f32x4 a0  = {0.f,0.f,0.f,0.f};
    f32x4 a1a = {0.f,0.f,0.f,0.f};
    f32x4 a1b = {0.f,0.f,0.f,0.f};
    a0  = MFMA16(w0h[0], ah[0], a0);                 // layer0 gates (K=64), depth 2
    a0  = MFMA16(w0h[1], ah[1], a0);
    a1a = MFMA16(w1h[0], ah[0], a1a);                // layer1 gates (K=128), 2 chains depth 2
    a1a = MFMA16(w1h[1], ah[1], a1a);
    a1b = MFMA16(w1h[2], ah[2], a1b);
    a1b = MFMA16(w1h[3], ah[3], a1b);
    const f32x4 a1 = a1a + a1b;

    const bool isL0 = (col < 8);
    const bool run = isL0 ? (t < TT) : (t > 0);      // uniform true for 0<t<TT
    if (run) {
        const float g0 = isL0 ? a0[0] : a1[0];
        const float g1 = isL0 ? a0[1] : a1[1];
        const float g2 = isL0 ? a0[2] : a1[2];
        const float g3 = isL0 ? a0[3] : a1[3];
        const float ii = fsig(g0), ff = fsig(g1);
        const float gg = ftanh(g2), oo = fsig(g3);
        const float c = ff * cst + ii * gg;
        cst = c;
        const float h = oo * ftanh(c);
        const int u = nt * 4 + q4;
        if (u < HH) {
            const unsigned short hs = f2h(h);
            if (isL0) {
                dA[col * AS + u] = hs;               // L0 recurrent
                dA[(col + 8) * AS + u] = hs;         // L1 input
            } else {
                dA[col * AS + 50 + u] = hs;          // L1 recurrent
                if (t == TT) hBf[(col - 8) * 52 + u] = h;
            }
        }
    }
}

// ---------------- main kernel: v16 + explicit 2-step unroll (static buffers) ----------------
// v17 lesson: 2 waves/SIMD is the sweet spot (fewer -> latency-exposed, more -> read
// inflation). This round shaves the serial chain: loop-invariant LDS addresses via
// even/odd unroll, a1 MFMA dependent-depth 4 -> 2+2.
__global__ __launch_bounds__(NTH, 2) void lstm_mfma_v18(
    const float* __restrict__ x,
    const unsigned short* __restrict__ ws,
    const float* __restrict__ fc_w, const float* __restrict__ fc_b,
    float* __restrict__ out)
{
    __shared__ __align__(16) unsigned short Ah[2][16 * AS];
    __shared__ float hBf[NB * 52];
    __shared__ unsigned short xstash[NB * XS];        // 8 x 1540 fp16 = 24.6 KB

    const int tid  = threadIdx.x;
    const int lane = tid & 63;
    const int wid  = tid >> 6;
    const int col  = lane & 15;
    const int q4   = lane >> 4;
    const int b0   = blockIdx.x * NB;

    for (int i = tid; i < 16 * AS; i += NTH) {
        Ah[0][i] = 0; Ah[1][i] = 0;
    }

    // ---- preload + fp16-convert the block's x slab (contiguous 48 KB) ----
    {
        const float* xg = x + (size_t)b0 * (TT * 3);
        for (int i = tid; i < (NB * TT * 3) / 4; i += NTH) {   // 3072 float4s, 6 iters
            const float4 v4 = ((const float4*)xg)[i];
            const int e = i * 4;
            #pragma unroll
            for (int j = 0; j < 4; ++j) {
                const int b = (e + j) / (TT * 3);
                const int r = (e + j) - b * (TT * 3);
                xstash[b * XS + r] = f2h((&v4.x)[j]);
            }
        }
    }
    __syncthreads();

    if (tid < NB) {                                   // bias columns (fp16 1.0), both buffers
        Ah[0][tid * AS + 53] = 0x3C00;        Ah[1][tid * AS + 53] = 0x3C00;
        Ah[0][(tid + 8) * AS + 100] = 0x3C00; Ah[1][(tid + 8) * AS + 100] = 0x3C00;
    }

    // ---- weight fragments (hi only): wave w owns tile w, plus tile 8+w if w<5 ----
    const half8* wsf = (const half8*)ws;
    half8 w0h[2][2], w1h[2][4];
    const bool has2 = (wid < 5);
    #pragma unroll
    for (int i = 0; i < 2; ++i) {
        const int nt = (i == 0) ? wid : 8 + wid;
        const bool v = (i == 0) || has2;
        const size_t gb = (size_t)(v ? nt : 0) * (12 * 64) + lane;
        #pragma unroll
        for (int kt = 0; kt < 2; ++kt)
            w0h[i][kt] = v ? wsf[gb + (size_t)(kt * 2 + 0) * 64] : half8{};
        #pragma unroll
        for (int kt = 0; kt < 4; ++kt)
            w1h[i][kt] = v ? wsf[gb + (size_t)(4 + kt * 2 + 0) * 64] : half8{};
    }

    // ---- x-writer role: wave 7 lanes 0..23 (1-tile wave) ----
    int xb = 0, xc = 0, xoff = 0;
    const bool isx = (tid >= 448 && tid < 448 + NB * 3);
    if (isx) {
        const int i = tid - 448;
        xb = i / 3; xc = i - xb * 3;
        xoff = xb * AS + 50 + xc;
        Ah[0][xoff] = xstash[xb * XS + xc];           // x(0) -> buf 0
    }
    float cst0 = 0.f, cst1 = 0.f;                     // c-state per owned tile
    __syncthreads();

    const int rbase = col * AS + q4 * 8;

    // ---- one timestep body; sA/dA are compile-time-fixed buffer halves ----
    #define STEP_BODY(T, sA, dA)                                               \
    {                                                                          \
        half8 ah[4];                                                           \
        ah[0] = *(const half8*)&sA[rbase];                                     \
        ah[1] = *(const half8*)&sA[rbase + 32];                                \
        ah[2] = *(const half8*)&sA[rbase + 64];                                \
        ah[3] = *(const half8*)&sA[rbase + 96];                                \
        tile_step(wid, (T), ah, w0h[0], w1h[0], cst0, col, q4, dA, hBf);       \
        if (has2)                                                              \
            tile_step(8 + wid, (T), ah, w0h[1], w1h[1], cst1, col, q4, dA, hBf);\
        if (isx) {                                                             \
            const int tn1 = ((T) + 1 < TT) ? ((T) + 1) : (TT - 1);             \
            dA[xoff] = xstash[xb * XS + tn1 * 3 + xc];                         \
        }                                                                      \
        __syncthreads();                                                       \
    }

    // ======== main loop: 2-step unroll, static even/odd buffers, 1 barrier/step ========
    for (int t = 0; t < TT; t += 2) {
        STEP_BODY(t,     Ah[0], Ah[1]);
        STEP_BODY(t + 1, Ah[1], Ah[0]);
    }
    STEP_BODY(TT, Ah[0], Ah[1]);                      // tail (t = TT, even)
    #undef STEP_BODY

    // ======== final FC ========
    if (tid < NB * 3) {
        const int bb = tid / 3, o = tid - bb * 3;
        float a = fc_b[o];
        #pragma unroll
        for (int uu = 0; uu < HH; ++uu)
            a += hBf[bb * 52 + uu] * fc_w[o * HH + uu];
        out[(size_t)(b0 + bb) * 3 + o] = a;
    }
}

extern "C" void kernel_launch(void* const* d_in, const int* in_sizes, int n_in,
                              void* d_out, int out_size, void* d_ws, size_t ws_size,
                              hipStream_t stream) {
    const float* x     = (const float*)d_in[0];
    const float* W_ih0 = (const float*)d_in[1];
    const float* W_hh0 = (const float*)d_in[2];
    const float* b_ih0 = (const float*)d_in[3];
    const float* b_hh0 = (const float*)d_in[4];
    const float* W_ih1 = (const float*)d_in[5];
    const float* W_hh1 = (const float*)d_in[6];
    const float* b_ih1 = (const float*)d_in[7];
    const float* b_hh1 = (const float*)d_in[8];
    const float* fc_w  = (const float*)d_in[9];
    const float* fc_b  = (const float*)d_in[10];
    float* out = (float*)d_out;
    unsigned short* ws = (unsigned short*)d_ws;       // NFRAG*64*16 B = 156 KB

    const int prepN = NFRAG * 64;
    prep_frags<<<(prepN + 255) / 256, 256, 0, stream>>>(
        W_ih0, W_hh0, b_ih0, b_hh0, W_ih1, W_hh1, b_ih1, b_hh1, ws);

    const int B = 2048;
    dim3 grid(B / NB), block(NTH);
    lstm_mfma_v18<<<grid, block, 0, stream>>>(x, ws, fc_w, fc_b, out);
}